// Round 3
// baseline (1722.098 us; speedup 1.0000x reference)
//
#include <hip/hip_runtime.h>
#include <stdint.h>

#define S 16384
#define D 4096
#define NE 64
#define CAP 320
#define KSPLIT 4
#define KCH (D / KSPLIT)   // 1024
#define RB 64              // rows per block in k1
#define K2ROWS 128
#define NB (S / K2ROWS)    // 128

__device__ __forceinline__ uint32_t rotl32(uint32_t v, int n) {
  return (v << n) | (v >> (32 - n));
}

// Bit-exact jax threefry for jax.random.uniform(jax.random.key(1), (S,), f32)
// under jax_threefry_partitionable=True (default since JAX 0.5.0):
//   counts = iota(u64, S); pair = (hi32=0, lo32=i); key = (0, 1)
//   bits[i] = out0 ^ out1   (32-bit path XORs the two threefry2x32 outputs)
__device__ uint32_t threefry_bits(int i) {
  const uint32_t k0 = 0u, k1 = 1u;
  const uint32_t ks2 = k0 ^ k1 ^ 0x1BD11BDAu;
  uint32_t x0 = 0u + k0;            // counts_hi + key0
  uint32_t x1 = (uint32_t)i + k1;   // counts_lo + key1
#define TFR(R) { x0 += x1; x1 = rotl32(x1, R); x1 ^= x0; }
  TFR(13) TFR(15) TFR(26) TFR(6)
  x0 += k1;  x1 += ks2 + 1u;
  TFR(17) TFR(29) TFR(16) TFR(24)
  x0 += ks2; x1 += k0 + 2u;
  TFR(13) TFR(15) TFR(26) TFR(6)
  x0 += k0;  x1 += k1 + 3u;
  TFR(17) TFR(29) TFR(16) TFR(24)
  x0 += k1;  x1 += ks2 + 4u;
  TFR(13) TFR(15) TFR(26) TFR(6)
  x0 += ks2; x1 += k0 + 5u;
#undef TFR
  return x0 ^ x1;
}

// ---- K1: partial logits. 1 thread = 1 row, acc over all 64 experts for one
// K-chunk. W accesses are wave-uniform -> scalar s_load; x via per-thread
// float4 (each lane consumes one full 64B line per chunk iteration).
// __launch_bounds__(RB, 1): min 1 wave/EU -> VGPR cap 512, so acc[64] stays
// in registers. (R2's launch_bounds(64) let the allocator target ~9 waves/SIMD
// at 56 VGPRs and spill all accumulators to scratch -> 1450 us.)
__global__ __launch_bounds__(RB, 1) void k1_logits(const float* __restrict__ x,
                                                   const float* __restrict__ Wg,
                                                   float* __restrict__ part) {
  const int rb = blockIdx.x >> 2;
  const int kc = blockIdx.x & 3;
  const int r = rb * RB + threadIdx.x;
  const float* __restrict__ xr = x + (size_t)r * D + kc * KCH;
  const float* __restrict__ wb = Wg + (size_t)kc * KCH;
  float acc[NE];
#pragma unroll
  for (int e = 0; e < NE; ++e) acc[e] = 0.0f;
  for (int kb = 0; kb < KCH; kb += 16) {
    float4 a0 = *(const float4*)(xr + kb + 0);
    float4 a1 = *(const float4*)(xr + kb + 4);
    float4 a2 = *(const float4*)(xr + kb + 8);
    float4 a3 = *(const float4*)(xr + kb + 12);
    float xk[16] = {a0.x, a0.y, a0.z, a0.w, a1.x, a1.y, a1.z, a1.w,
                    a2.x, a2.y, a2.z, a2.w, a3.x, a3.y, a3.z, a3.w};
#pragma unroll
    for (int e = 0; e < NE; ++e) {
      const float* __restrict__ w = wb + (size_t)e * D + kb;
#pragma unroll
      for (int kk = 0; kk < 16; ++kk) acc[e] = fmaf(xk[kk], w[kk], acc[e]);
    }
  }
  float* __restrict__ po = part + ((size_t)kc * S + r) * NE;
#pragma unroll
  for (int e = 0; e < NE; e += 4)
    *(float4*)(po + e) = make_float4(acc[e], acc[e + 1], acc[e + 2], acc[e + 3]);
}

// ---- K1b: reduce partials, softmax, top-2 (lower-index tie-break), RNG.
// One wave per row, lane = expert.
__global__ __launch_bounds__(256) void k1b_reduce(const float* __restrict__ part,
                                                  int* __restrict__ E1, int* __restrict__ E2,
                                                  int* __restrict__ WANT,
                                                  float* __restrict__ G1, float* __restrict__ G2) {
  const int row = blockIdx.x * 4 + (threadIdx.x >> 6);
  const int lane = threadIdx.x & 63;
  float l = 0.0f;
#pragma unroll
  for (int c = 0; c < KSPLIT; ++c)
    l += part[((size_t)c * S + row) * NE + lane];

  float m = l;
#pragma unroll
  for (int off = 32; off; off >>= 1) m = fmaxf(m, __shfl_xor(m, off));
  float ex = expf(l - m);
  float ssum = ex;
#pragma unroll
  for (int off = 32; off; off >>= 1) ssum += __shfl_xor(ssum, off);
  ssum = __shfl(ssum, 0);               // single denominator like the reference
  float gate = ex / ssum;

  // top-1: max value, tie -> lower lane
  float v = gate; int id = lane;
#pragma unroll
  for (int off = 32; off; off >>= 1) {
    float vo = __shfl_xor(v, off); int io = __shfl_xor(id, off);
    if (vo > v || (vo == v && io < id)) { v = vo; id = io; }
  }
  const float g1 = v; const int e1 = id;
  float gate2 = (lane == e1) ? -1.0f : gate;
  v = gate2; id = lane;
#pragma unroll
  for (int off = 32; off; off >>= 1) {
    float vo = __shfl_xor(v, off); int io = __shfl_xor(id, off);
    if (vo > v || (vo == v && io < id)) { v = vo; id = io; }
  }
  const float g2 = v; const int e2 = id;

  if (lane == 0) {
    const float denom = g1 + g2;
    const float g1n = g1 / denom;
    const float g2n = g2 / denom;
    const uint32_t bits = threefry_bits(row);
    const float rnd = __uint_as_float((bits >> 9) | 0x3f800000u) - 1.0f;
    E1[row] = e1; E2[row] = e2;
    WANT[row] = (rnd < 2.0f * g2n) ? 1 : 0;
    G1[row] = g1n; G2[row] = g2n;
  }
}

// ---- K2: per-block (128 rows) local ranks + histograms for both streams.
__global__ __launch_bounds__(K2ROWS) void k2_rank(const int* __restrict__ E1,
                                                  const int* __restrict__ E2,
                                                  const int* __restrict__ WANT,
                                                  int* __restrict__ LR1, int* __restrict__ LR2,
                                                  int* __restrict__ H1, int* __restrict__ H2) {
  __shared__ unsigned char s1[K2ROWS], s2[K2ROWS];
  __shared__ int h1[NE], h2[NE];
  const int b = blockIdx.x, t = threadIdx.x;
  const int r = b * K2ROWS + t;
  if (t < NE) { h1[t] = 0; h2[t] = 0; }
  const int e1 = E1[r];
  const int e2 = WANT[r] ? E2[r] : NE;  // sentinel = excluded
  s1[t] = (unsigned char)e1;
  s2[t] = (unsigned char)e2;
  __syncthreads();
  int r1 = 0, r2 = 0;
  for (int j = 0; j < t; ++j) {
    r1 += (s1[j] == e1);
    r2 += (s2[j] == e2);
  }
  LR1[r] = r1; LR2[r] = r2;
  atomicAdd(&h1[e1], 1);
  if (e2 < NE) atomicAdd(&h2[e2], 1);
  __syncthreads();
  if (t < NE) { H1[b * NE + t] = h1[t]; H2[b * NE + t] = h2[t]; }
}

// ---- K3: exclusive prefix over blocks per expert + counts1 -> remaining cap2.
__global__ void k3_prefix(const int* __restrict__ H1, const int* __restrict__ H2,
                          int* __restrict__ OFF1, int* __restrict__ OFF2,
                          int* __restrict__ REM2) {
  const int e = threadIdx.x;  // 64 threads
  int run1 = 0, run2 = 0;
  for (int b = 0; b < NB; ++b) {
    OFF1[b * NE + e] = run1; run1 += H1[b * NE + e];
    OFF2[b * NE + e] = run2; run2 += H2[b * NE + e];
  }
  REM2[e] = CAP - min(run1, CAP);
}

// ---- K4: apply capacity decisions, scatter into (pre-zeroed) combine.
__global__ __launch_bounds__(256) void k4_scatter(const int* __restrict__ E1,
                                                  const int* __restrict__ E2,
                                                  const int* __restrict__ WANT,
                                                  const float* __restrict__ G1,
                                                  const float* __restrict__ G2,
                                                  const int* __restrict__ LR1,
                                                  const int* __restrict__ LR2,
                                                  const int* __restrict__ OFF1,
                                                  const int* __restrict__ OFF2,
                                                  const int* __restrict__ REM2,
                                                  float* __restrict__ out) {
  const int r = blockIdx.x * 256 + threadIdx.x;
  const int b = r / K2ROWS;
  const int e1 = E1[r];
  const int pos1 = OFF1[b * NE + e1] + LR1[r] + 1;
  if (pos1 <= CAP) out[(size_t)r * NE + e1] = G1[r];
  if (WANT[r]) {
    const int e2 = E2[r];
    const int pos2 = OFF2[b * NE + e2] + LR2[r] + 1;
    if (pos2 <= REM2[e2]) out[(size_t)r * NE + e2] = G2[r];
  }
}

extern "C" void kernel_launch(void* const* d_in, const int* in_sizes, int n_in,
                              void* d_out, int out_size, void* d_ws, size_t ws_size,
                              hipStream_t stream) {
  const float* x  = (const float*)d_in[0];
  const float* Wg = (const float*)d_in[1];
  float* out = (float*)d_out;
  char* ws = (char*)d_ws;

  float* part = (float*)ws;
  size_t off = (size_t)KSPLIT * S * NE * sizeof(float);  // 16 MB
  int*   E1   = (int*)(ws + off);   off += (size_t)S * 4;
  int*   E2   = (int*)(ws + off);   off += (size_t)S * 4;
  int*   WANT = (int*)(ws + off);   off += (size_t)S * 4;
  float* G1   = (float*)(ws + off); off += (size_t)S * 4;
  float* G2   = (float*)(ws + off); off += (size_t)S * 4;
  int*   LR1  = (int*)(ws + off);   off += (size_t)S * 4;
  int*   LR2  = (int*)(ws + off);   off += (size_t)S * 4;
  int*   H1   = (int*)(ws + off);   off += (size_t)NB * NE * 4;
  int*   H2   = (int*)(ws + off);   off += (size_t)NB * NE * 4;
  int*   OFF1 = (int*)(ws + off);   off += (size_t)NB * NE * 4;
  int*   OFF2 = (int*)(ws + off);   off += (size_t)NB * NE * 4;
  int*   REM2 = (int*)(ws + off);   off += (size_t)NE * 4;

  hipMemsetAsync(d_out, 0, (size_t)out_size * sizeof(float), stream);
  k1_logits<<<(S / RB) * KSPLIT, RB, 0, stream>>>(x, Wg, part);
  k1b_reduce<<<S / 4, 256, 0, stream>>>(part, E1, E2, WANT, G1, G2);
  k2_rank<<<NB, K2ROWS, 0, stream>>>(E1, E2, WANT, LR1, LR2, H1, H2);
  k3_prefix<<<1, NE, 0, stream>>>(H1, H2, OFF1, OFF2, REM2);
  k4_scatter<<<S / 256, 256, 0, stream>>>(E1, E2, WANT, G1, G2, LR1, LR2, OFF1, OFF2, REM2, out);
}

// Round 4
// 427.274 us; speedup vs baseline: 4.0304x; 4.0304x over previous
//
#include <hip/hip_runtime.h>
#include <stdint.h>

#define S 16384
#define D 4096
#define NE 64
#define CAP 320
#define KSPLIT 4
#define KCH (D / KSPLIT)   // 1024 K per block
#define TM 64              // rows per block tile
#define KB 32              // K chunk staged in LDS
#define PADLD 68           // 64 + 4: 16B-aligned, breaks bank-conflict strides
#define K2ROWS 128
#define NB (S / K2ROWS)    // 128

__device__ __forceinline__ uint32_t rotl32(uint32_t v, int n) {
  return (v << n) | (v >> (32 - n));
}

// Bit-exact jax threefry for jax.random.uniform(jax.random.key(1), (S,), f32)
// under jax_threefry_partitionable=True (default since JAX 0.5.0):
//   counts = iota(u64, S); pair = (hi32=0, lo32=i); key = (0, 1)
//   bits[i] = out0 ^ out1   (32-bit path XORs the two threefry2x32 outputs)
__device__ uint32_t threefry_bits(int i) {
  const uint32_t k0 = 0u, k1 = 1u;
  const uint32_t ks2 = k0 ^ k1 ^ 0x1BD11BDAu;
  uint32_t x0 = 0u + k0;            // counts_hi + key0
  uint32_t x1 = (uint32_t)i + k1;   // counts_lo + key1
#define TFR(R) { x0 += x1; x1 = rotl32(x1, R); x1 ^= x0; }
  TFR(13) TFR(15) TFR(26) TFR(6)
  x0 += k1;  x1 += ks2 + 1u;
  TFR(17) TFR(29) TFR(16) TFR(24)
  x0 += ks2; x1 += k0 + 2u;
  TFR(13) TFR(15) TFR(26) TFR(6)
  x0 += k0;  x1 += k1 + 3u;
  TFR(17) TFR(29) TFR(16) TFR(24)
  x0 += k1;  x1 += ks2 + 4u;
  TFR(13) TFR(15) TFR(26) TFR(6)
  x0 += ks2; x1 += k0 + 5u;
#undef TFR
  return x0 ^ x1;
}

// ---- K1: LDS-tiled fp32 GEMM (no fp32 MFMA on CDNA4 -> VALU).
// Tile: 64 rows x 64 experts x KB=32. 256 threads, each owns a 4x4 register
// tile (acc[4][4] -- small enough that the allocator can't justify spilling;
// R2/R3's acc[64]-per-thread spilled to scratch at VGPR=56 and ran 26x slow).
// Both LDS tiles K-major [k][64+pad]: compute reads are ds_read_b128,
// conflict-free; staging scatter-writes are 4-way (1.58x) but ~1/8 of traffic.
__global__ __launch_bounds__(256, 4) void k1_logits(const float* __restrict__ x,
                                                    const float* __restrict__ Wg,
                                                    float* __restrict__ part) {
  __shared__ float xs[KB][PADLD];
  __shared__ float ws[KB][PADLD];
  const int kc = blockIdx.x & (KSPLIT - 1);
  const int rb = blockIdx.x >> 2;
  const int rowBase = rb * TM;
  const int kOff = kc * KCH;
  const int t = threadIdx.x;
  const int tx = t & 15;    // expert group: experts 4*tx .. 4*tx+3
  const int ty = t >> 4;    // row group:    rows    4*ty .. 4*ty+3
  const int srow = t >> 3;  // staging: rows 0..31 (+32 second half)
  const int skq = t & 7;    // staging: k-quad 0..7 (32 K per chunk)

  float acc[4][4];
#pragma unroll
  for (int i = 0; i < 4; ++i)
#pragma unroll
    for (int j = 0; j < 4; ++j) acc[i][j] = 0.0f;

  for (int kb = 0; kb < KCH; kb += KB) {
    // ---- stage 64x32 of x and W (each thread: 2 float4 of each) ----
#pragma unroll
    for (int half = 0; half < 2; ++half) {
      const int row = srow + half * 32;
      const size_t gk = (size_t)kOff + kb + 4 * skq;
      const float4 xv = *(const float4*)&x[(size_t)(rowBase + row) * D + gk];
      const float4 wv = *(const float4*)&Wg[(size_t)row * D + gk];
      xs[4 * skq + 0][row] = xv.x;
      xs[4 * skq + 1][row] = xv.y;
      xs[4 * skq + 2][row] = xv.z;
      xs[4 * skq + 3][row] = xv.w;
      ws[4 * skq + 0][row] = wv.x;
      ws[4 * skq + 1][row] = wv.y;
      ws[4 * skq + 2][row] = wv.z;
      ws[4 * skq + 3][row] = wv.w;
    }
    __syncthreads();
    // ---- compute: per kk, 2 x ds_read_b128 + 16 FMA ----
#pragma unroll
    for (int kk = 0; kk < KB; ++kk) {
      const float4 xv = *(const float4*)&xs[kk][4 * ty];
      const float4 wv = *(const float4*)&ws[kk][4 * tx];
      const float xr[4] = {xv.x, xv.y, xv.z, xv.w};
      const float wr[4] = {wv.x, wv.y, wv.z, wv.w};
#pragma unroll
      for (int i = 0; i < 4; ++i)
#pragma unroll
        for (int j = 0; j < 4; ++j) acc[i][j] = fmaf(xr[i], wr[j], acc[i][j]);
    }
    __syncthreads();
  }
  // ---- epilogue: partials, [kc][S][NE] layout ----
#pragma unroll
  for (int i = 0; i < 4; ++i) {
    float* __restrict__ po =
        part + ((size_t)kc * S + rowBase + 4 * ty + i) * NE + 4 * tx;
    *(float4*)po = make_float4(acc[i][0], acc[i][1], acc[i][2], acc[i][3]);
  }
}

// ---- K1b: reduce partials, softmax, top-2 (lower-index tie-break), RNG.
// One wave per row, lane = expert.
__global__ __launch_bounds__(256) void k1b_reduce(const float* __restrict__ part,
                                                  int* __restrict__ E1, int* __restrict__ E2,
                                                  int* __restrict__ WANT,
                                                  float* __restrict__ G1, float* __restrict__ G2) {
  const int row = blockIdx.x * 4 + (threadIdx.x >> 6);
  const int lane = threadIdx.x & 63;
  float l = 0.0f;
#pragma unroll
  for (int c = 0; c < KSPLIT; ++c)
    l += part[((size_t)c * S + row) * NE + lane];

  float m = l;
#pragma unroll
  for (int off = 32; off; off >>= 1) m = fmaxf(m, __shfl_xor(m, off));
  float ex = expf(l - m);
  float ssum = ex;
#pragma unroll
  for (int off = 32; off; off >>= 1) ssum += __shfl_xor(ssum, off);
  ssum = __shfl(ssum, 0);               // single denominator like the reference
  float gate = ex / ssum;

  // top-1: max value, tie -> lower lane
  float v = gate; int id = lane;
#pragma unroll
  for (int off = 32; off; off >>= 1) {
    float vo = __shfl_xor(v, off); int io = __shfl_xor(id, off);
    if (vo > v || (vo == v && io < id)) { v = vo; id = io; }
  }
  const float g1 = v; const int e1 = id;
  float gate2 = (lane == e1) ? -1.0f : gate;
  v = gate2; id = lane;
#pragma unroll
  for (int off = 32; off; off >>= 1) {
    float vo = __shfl_xor(v, off); int io = __shfl_xor(id, off);
    if (vo > v || (vo == v && io < id)) { v = vo; id = io; }
  }
  const float g2 = v; const int e2 = id;

  if (lane == 0) {
    const float denom = g1 + g2;
    const float g1n = g1 / denom;
    const float g2n = g2 / denom;
    const uint32_t bits = threefry_bits(row);
    const float rnd = __uint_as_float((bits >> 9) | 0x3f800000u) - 1.0f;
    E1[row] = e1; E2[row] = e2;
    WANT[row] = (rnd < 2.0f * g2n) ? 1 : 0;
    G1[row] = g1n; G2[row] = g2n;
  }
}

// ---- K2: per-block (128 rows) local ranks + histograms for both streams.
__global__ __launch_bounds__(K2ROWS) void k2_rank(const int* __restrict__ E1,
                                                  const int* __restrict__ E2,
                                                  const int* __restrict__ WANT,
                                                  int* __restrict__ LR1, int* __restrict__ LR2,
                                                  int* __restrict__ H1, int* __restrict__ H2) {
  __shared__ unsigned char s1[K2ROWS], s2[K2ROWS];
  __shared__ int h1[NE], h2[NE];
  const int b = blockIdx.x, t = threadIdx.x;
  const int r = b * K2ROWS + t;
  if (t < NE) { h1[t] = 0; h2[t] = 0; }
  const int e1 = E1[r];
  const int e2 = WANT[r] ? E2[r] : NE;  // sentinel = excluded
  s1[t] = (unsigned char)e1;
  s2[t] = (unsigned char)e2;
  __syncthreads();
  int r1 = 0, r2 = 0;
  for (int j = 0; j < t; ++j) {
    r1 += (s1[j] == e1);
    r2 += (s2[j] == e2);
  }
  LR1[r] = r1; LR2[r] = r2;
  atomicAdd(&h1[e1], 1);
  if (e2 < NE) atomicAdd(&h2[e2], 1);
  __syncthreads();
  if (t < NE) { H1[b * NE + t] = h1[t]; H2[b * NE + t] = h2[t]; }
}

// ---- K3: exclusive prefix over blocks per expert + counts1 -> remaining cap2.
__global__ void k3_prefix(const int* __restrict__ H1, const int* __restrict__ H2,
                          int* __restrict__ OFF1, int* __restrict__ OFF2,
                          int* __restrict__ REM2) {
  const int e = threadIdx.x;  // 64 threads
  int run1 = 0, run2 = 0;
  for (int b = 0; b < NB; ++b) {
    OFF1[b * NE + e] = run1; run1 += H1[b * NE + e];
    OFF2[b * NE + e] = run2; run2 += H2[b * NE + e];
  }
  REM2[e] = CAP - min(run1, CAP);
}

// ---- K4: apply capacity decisions, scatter into (pre-zeroed) combine.
__global__ __launch_bounds__(256) void k4_scatter(const int* __restrict__ E1,
                                                  const int* __restrict__ E2,
                                                  const int* __restrict__ WANT,
                                                  const float* __restrict__ G1,
                                                  const float* __restrict__ G2,
                                                  const int* __restrict__ LR1,
                                                  const int* __restrict__ LR2,
                                                  const int* __restrict__ OFF1,
                                                  const int* __restrict__ OFF2,
                                                  const int* __restrict__ REM2,
                                                  float* __restrict__ out) {
  const int r = blockIdx.x * 256 + threadIdx.x;
  const int b = r / K2ROWS;
  const int e1 = E1[r];
  const int pos1 = OFF1[b * NE + e1] + LR1[r] + 1;
  if (pos1 <= CAP) out[(size_t)r * NE + e1] = G1[r];
  if (WANT[r]) {
    const int e2 = E2[r];
    const int pos2 = OFF2[b * NE + e2] + LR2[r] + 1;
    if (pos2 <= REM2[e2]) out[(size_t)r * NE + e2] = G2[r];
  }
}

extern "C" void kernel_launch(void* const* d_in, const int* in_sizes, int n_in,
                              void* d_out, int out_size, void* d_ws, size_t ws_size,
                              hipStream_t stream) {
  const float* x  = (const float*)d_in[0];
  const float* Wg = (const float*)d_in[1];
  float* out = (float*)d_out;
  char* ws = (char*)d_ws;

  float* part = (float*)ws;
  size_t off = (size_t)KSPLIT * S * NE * sizeof(float);  // 16 MB
  int*   E1   = (int*)(ws + off);   off += (size_t)S * 4;
  int*   E2   = (int*)(ws + off);   off += (size_t)S * 4;
  int*   WANT = (int*)(ws + off);   off += (size_t)S * 4;
  float* G1   = (float*)(ws + off); off += (size_t)S * 4;
  float* G2   = (float*)(ws + off); off += (size_t)S * 4;
  int*   LR1  = (int*)(ws + off);   off += (size_t)S * 4;
  int*   LR2  = (int*)(ws + off);   off += (size_t)S * 4;
  int*   H1   = (int*)(ws + off);   off += (size_t)NB * NE * 4;
  int*   H2   = (int*)(ws + off);   off += (size_t)NB * NE * 4;
  int*   OFF1 = (int*)(ws + off);   off += (size_t)NB * NE * 4;
  int*   OFF2 = (int*)(ws + off);   off += (size_t)NB * NE * 4;
  int*   REM2 = (int*)(ws + off);   off += (size_t)NE * 4;

  hipMemsetAsync(d_out, 0, (size_t)out_size * sizeof(float), stream);
  k1_logits<<<(S / TM) * KSPLIT, 256, 0, stream>>>(x, Wg, part);
  k1b_reduce<<<S / 4, 256, 0, stream>>>(part, E1, E2, WANT, G1, G2);
  k2_rank<<<NB, K2ROWS, 0, stream>>>(E1, E2, WANT, LR1, LR2, H1, H2);
  k3_prefix<<<1, NE, 0, stream>>>(H1, H2, OFF1, OFF2, REM2);
  k4_scatter<<<S / 256, 256, 0, stream>>>(E1, E2, WANT, G1, G2, LR1, LR2, OFF1, OFF2, REM2, out);
}